// Round 9
// baseline (158.985 us; speedup 1.0000x reference)
//
#include <hip/hip_runtime.h>
#include <hip/hip_bf16.h>

#define N     8192
#define FIN   256
#define FOUT  64
#define ALPHA 0.2f
#define KQ    8               // j-octants
#define JQ    (N / KQ)        // 1024 j per attn block
#define JW    256             // j per wave
#define NS    8               // MFMA K-steps per wave (JW/32)
#define RB    32              // rows per attn block (two 16-row A-tiles)
#define PACKB 16384           // pack blocks inside k_hp (one-shot waves)
#define NSPAN (N * N / 256)   // 262144 spans of 256 ints

typedef __attribute__((ext_vector_type(8))) short bf16x8;
typedef __attribute__((ext_vector_type(4))) float f32x4;
typedef __attribute__((ext_vector_type(4))) int   i32x4;
typedef unsigned long long ull;
typedef __attribute__((ext_vector_type(2))) ull u64x2;

static __device__ __forceinline__ unsigned short f2bf(float x) {
    union { float f; unsigned int u; } v; v.f = x;
    unsigned int r = v.u + 0x7FFFu + ((v.u >> 16) & 1u);   // RNE
    return (unsigned short)(r >> 16);
}
static __device__ __forceinline__ float asf(unsigned int u) {
    union { unsigned int u; float f; } v; v.u = u; return v.f;
}
// exp(leaky_relu(a+b)); scores bounded (~15) -> no softmax shift needed
static __device__ __forceinline__ float wexp(float a, float b) {
    const float e = a + b;
    return __expf(fmaxf(e, ALPHA * e));
}

// ---- kernel 1 (fused): adj -> ballot bitmask (fill-shaped)  +  h = X@W ----
// mask layout: span sp = 256 consecutive ints; word w (0..3): bit l <->
// adj[sp*256 + l*4 + w]  (ballot-native order, consumer decodes)
__global__ __launch_bounds__(256) void k_hp(
        const float* __restrict__ X, const float* __restrict__ W,
        const float* __restrict__ a1, const float* __restrict__ a2,
        const int* __restrict__ adj, unsigned short* __restrict__ hb,
        float* __restrict__ f1, float* __restrict__ f2,
        ull* __restrict__ mask) {
    const int lane = threadIdx.x & 63;
    const int wvv  = threadIdx.x >> 6;
    const int b    = blockIdx.x;

    if (b < PACKB) {
        // ---------- one-shot pack wave: 4 spans = 4 KB, then done ----------
        const size_t sp0 = ((size_t)b * 4 + wvv) * 4;    // 4 consecutive spans
        const int* base = adj + sp0 * 256 + lane * 4;

        const i32x4 v0 = *(const i32x4*)(base);
        const i32x4 v1 = *(const i32x4*)(base + 256);
        const i32x4 v2 = *(const i32x4*)(base + 512);
        const i32x4 v3 = *(const i32x4*)(base + 768);

        const u64x2 m00 = (u64x2){__ballot(v0.x > 0), __ballot(v0.y > 0)};
        const u64x2 m01 = (u64x2){__ballot(v0.z > 0), __ballot(v0.w > 0)};
        const u64x2 m10 = (u64x2){__ballot(v1.x > 0), __ballot(v1.y > 0)};
        const u64x2 m11 = (u64x2){__ballot(v1.z > 0), __ballot(v1.w > 0)};
        const u64x2 m20 = (u64x2){__ballot(v2.x > 0), __ballot(v2.y > 0)};
        const u64x2 m21 = (u64x2){__ballot(v2.z > 0), __ballot(v2.w > 0)};
        const u64x2 m30 = (u64x2){__ballot(v3.x > 0), __ballot(v3.y > 0)};
        const u64x2 m31 = (u64x2){__ballot(v3.z > 0), __ballot(v3.w > 0)};

        if (lane == 0) {
            u64x2* mp = (u64x2*)(mask + sp0 * 4);
            mp[0] = m00; mp[1] = m01; mp[2] = m10; mp[3] = m11;
            mp[4] = m20; mp[5] = m21; mp[6] = m30; mp[7] = m31;
        }
    } else {
        // ---------- h = X@W -> hb[j/8][col][8], f1, f2 ----------
        const int row0 = ((b - PACKB) * 4 + wvv) * 4;

        const float4* Xr[4];
        #pragma unroll
        for (int r = 0; r < 4; ++r)
            Xr[r] = (const float4*)(X + (size_t)(row0 + r) * FIN);

        float acc[4] = {0.f, 0.f, 0.f, 0.f};
        #pragma unroll 4
        for (int k4 = 0; k4 < FIN / 4; ++k4) {
            const float w0 = W[(k4 * 4 + 0) * FOUT + lane];
            const float w1 = W[(k4 * 4 + 1) * FOUT + lane];
            const float w2 = W[(k4 * 4 + 2) * FOUT + lane];
            const float w3 = W[(k4 * 4 + 3) * FOUT + lane];
            #pragma unroll
            for (int r = 0; r < 4; ++r) {
                const float4 xv = Xr[r][k4];
                acc[r] = fmaf(xv.x, w0, acc[r]);
                acc[r] = fmaf(xv.y, w1, acc[r]);
                acc[r] = fmaf(xv.z, w2, acc[r]);
                acc[r] = fmaf(xv.w, w3, acc[r]);
            }
        }

        ushort4 hv;
        hv.x = f2bf(acc[0]); hv.y = f2bf(acc[1]);
        hv.z = f2bf(acc[2]); hv.w = f2bf(acc[3]);
        *(ushort4*)&hb[(size_t)(row0 >> 3) * 512 + lane * 8 + (row0 & 7)] = hv;

        const float a1v = a1[lane];
        const float a2v = a2[lane];
        #pragma unroll
        for (int r = 0; r < 4; ++r) {
            float p1 = acc[r] * a1v;
            float p2 = acc[r] * a2v;
            #pragma unroll
            for (int off = 32; off > 0; off >>= 1) {
                p1 += __shfl_down(p1, off);
                p2 += __shfl_down(p2, off);
            }
            if (lane == 0) { f1[row0 + r] = p1; f2[row0 + r] = p2; }
        }
    }
}

// -------- kernel 2: bitmask-driven MFMA attention partial sums --------
// block: 32 rows (two 16-row tiles) x 1024-j octant; wave owns 256 j.
__global__ __launch_bounds__(256, 4) void k_attn(
        const ull* __restrict__ mask, const unsigned short* __restrict__ hb,
        const float* __restrict__ f1, const float* __restrict__ f2,
        float* __restrict__ part, float* __restrict__ pden) {
    __shared__ f32x4 redA[2][256];    // 8 KB
    __shared__ f32x4 redB[2][256];    // 8 KB
    __shared__ float dred[4][32];

    const int t    = threadIdx.x;
    const int lane = t & 63;
    const int wv   = t >> 6;
    const int bid  = blockIdx.x;
    const int rg   = bid >> 3;
    const int q    = bid & 7;
    const int i0   = rg * RB;
    const int r    = lane & 15;
    const int kg   = lane >> 4;

    const int jw = q * JQ + wv * JW;
    const float f1a = f1[i0 + r];
    const float f1b = f1[i0 + 16 + r];
    const float* f2p = f2 + jw + kg * 8;
    const unsigned short* hbp = hb + (size_t)(jw >> 3) * 512 + kg * 512 + r * 8;

    // the wave's whole 256-j mask window: 4 words per row, 2 rows
    const ull* mpa = mask + ((size_t)(i0 + r) * 32 + (jw >> 8)) * 4;
    const ull* mpb = mask + ((size_t)(i0 + 16 + r) * 32 + (jw >> 8)) * 4;
    const ull ma0 = mpa[0], ma1 = mpa[1], ma2 = mpa[2], ma3 = mpa[3];
    const ull mb0 = mpb[0], mb1 = mpb[1], mb2 = mpb[2], mb3 = mpb[3];

    f32x4 accA[4], accB[4];
    #pragma unroll
    for (int c = 0; c < 4; ++c) {
        accA[c] = (f32x4){0.f, 0.f, 0.f, 0.f};
        accB[c] = (f32x4){0.f, 0.f, 0.f, 0.f};
    }
    float sacc0 = 0.f, sacc1 = 0.f;
    const int sh0 = kg * 2;

    #pragma unroll
    for (int s = 0; s < NS; ++s) {
        const unsigned short* hs = hbp + s * 2048;
        const bf16x8 bf0 = *(const bf16x8*)(hs);
        const bf16x8 bf1 = *(const bf16x8*)(hs + 128);
        const bf16x8 bf2 = *(const bf16x8*)(hs + 256);
        const bf16x8 bf3 = *(const bf16x8*)(hs + 384);

        const float4 fa = *(const float4*)(f2p + s * 32);
        const float4 fb = *(const float4*)(f2p + s * 32 + 4);

        // bits: j-offset o = s*32 + kg*8 + u -> word u&3, bit s*8+kg*2+(u>>2)
        const int sh = sh0 + s * 8;
        const unsigned ta0 = (unsigned)(ma0 >> sh) & 3u;
        const unsigned ta1 = (unsigned)(ma1 >> sh) & 3u;
        const unsigned ta2 = (unsigned)(ma2 >> sh) & 3u;
        const unsigned ta3 = (unsigned)(ma3 >> sh) & 3u;
        const unsigned tb0 = (unsigned)(mb0 >> sh) & 3u;
        const unsigned tb1 = (unsigned)(mb1 >> sh) & 3u;
        const unsigned tb2 = (unsigned)(mb2 >> sh) & 3u;
        const unsigned tb3 = (unsigned)(mb3 >> sh) & 3u;

        // ---- tile A (rows i0..i0+15) ----
        {
            const float w0 = (ta0 & 1u) ? wexp(f1a, fa.x) : 0.f;
            const float w1 = (ta1 & 1u) ? wexp(f1a, fa.y) : 0.f;
            const float w2 = (ta2 & 1u) ? wexp(f1a, fa.z) : 0.f;
            const float w3 = (ta3 & 1u) ? wexp(f1a, fa.w) : 0.f;
            const float w4 = (ta0 & 2u) ? wexp(f1a, fb.x) : 0.f;
            const float w5 = (ta1 & 2u) ? wexp(f1a, fb.y) : 0.f;
            const float w6 = (ta2 & 2u) ? wexp(f1a, fb.z) : 0.f;
            const float w7 = (ta3 & 2u) ? wexp(f1a, fb.w) : 0.f;
            union { bf16x8 v; __hip_bfloat162 h2[4]; unsigned u[4]; } af;
            af.h2[0] = __float22bfloat162_rn(make_float2(w0, w1));
            af.h2[1] = __float22bfloat162_rn(make_float2(w2, w3));
            af.h2[2] = __float22bfloat162_rn(make_float2(w4, w5));
            af.h2[3] = __float22bfloat162_rn(make_float2(w6, w7));
            float ds = 0.f;
            #pragma unroll
            for (int u = 0; u < 4; ++u)
                ds += asf(af.u[u] << 16) + asf(af.u[u] & 0xFFFF0000u);
            sacc0 += ds;
            accA[0] = __builtin_amdgcn_mfma_f32_16x16x32_bf16(af.v, bf0, accA[0], 0, 0, 0);
            accA[1] = __builtin_amdgcn_mfma_f32_16x16x32_bf16(af.v, bf1, accA[1], 0, 0, 0);
            accA[2] = __builtin_amdgcn_mfma_f32_16x16x32_bf16(af.v, bf2, accA[2], 0, 0, 0);
            accA[3] = __builtin_amdgcn_mfma_f32_16x16x32_bf16(af.v, bf3, accA[3], 0, 0, 0);
        }
        // ---- tile B (rows i0+16..i0+31), reuses the same B-fragments ----
        {
            const float w0 = (tb0 & 1u) ? wexp(f1b, fa.x) : 0.f;
            const float w1 = (tb1 & 1u) ? wexp(f1b, fa.y) : 0.f;
            const float w2 = (tb2 & 1u) ? wexp(f1b, fa.z) : 0.f;
            const float w3 = (tb3 & 1u) ? wexp(f1b, fa.w) : 0.f;
            const float w4 = (tb0 & 2u) ? wexp(f1b, fb.x) : 0.f;
            const float w5 = (tb1 & 2u) ? wexp(f1b, fb.y) : 0.f;
            const float w6 = (tb2 & 2u) ? wexp(f1b, fb.z) : 0.f;
            const float w7 = (tb3 & 2u) ? wexp(f1b, fb.w) : 0.f;
            union { bf16x8 v; __hip_bfloat162 h2[4]; unsigned u[4]; } af;
            af.h2[0] = __float22bfloat162_rn(make_float2(w0, w1));
            af.h2[1] = __float22bfloat162_rn(make_float2(w2, w3));
            af.h2[2] = __float22bfloat162_rn(make_float2(w4, w5));
            af.h2[3] = __float22bfloat162_rn(make_float2(w6, w7));
            float ds = 0.f;
            #pragma unroll
            for (int u = 0; u < 4; ++u)
                ds += asf(af.u[u] << 16) + asf(af.u[u] & 0xFFFF0000u);
            sacc1 += ds;
            accB[0] = __builtin_amdgcn_mfma_f32_16x16x32_bf16(af.v, bf0, accB[0], 0, 0, 0);
            accB[1] = __builtin_amdgcn_mfma_f32_16x16x32_bf16(af.v, bf1, accB[1], 0, 0, 0);
            accB[2] = __builtin_amdgcn_mfma_f32_16x16x32_bf16(af.v, bf2, accB[2], 0, 0, 0);
            accB[3] = __builtin_amdgcn_mfma_f32_16x16x32_bf16(af.v, bf3, accB[3], 0, 0, 0);
        }
    }

    // ---- denominators: lanes l, l+16, l+32, l+48 share a row ----
    sacc0 += __shfl_xor(sacc0, 16); sacc0 += __shfl_xor(sacc0, 32);
    sacc1 += __shfl_xor(sacc1, 16); sacc1 += __shfl_xor(sacc1, 32);
    if (lane < 16) { dred[wv][lane] = sacc0; dred[wv][16 + lane] = sacc1; }

    // ---- acc tree-reduce across the 4 waves (both tiles in parallel) ----
    __syncthreads();
    if (wv >= 2) {
        #pragma unroll
        for (int cg = 0; cg < 4; ++cg) {
            redA[wv - 2][lane * 4 + cg] = accA[cg];
            redB[wv - 2][lane * 4 + cg] = accB[cg];
        }
    }
    __syncthreads();
    if (wv < 2) {
        #pragma unroll
        for (int cg = 0; cg < 4; ++cg) {
            accA[cg] += redA[wv][lane * 4 + cg];
            accB[cg] += redB[wv][lane * 4 + cg];
        }
    }
    __syncthreads();
    if (wv == 1) {
        #pragma unroll
        for (int cg = 0; cg < 4; ++cg) {
            redA[0][lane * 4 + cg] = accA[cg];
            redB[0][lane * 4 + cg] = accB[cg];
        }
    }
    __syncthreads();
    if (wv == 0) {
        #pragma unroll
        for (int cg = 0; cg < 4; ++cg) {
            accA[cg] += redA[0][lane * 4 + cg];
            accB[cg] += redB[0][lane * 4 + cg];
        }
        // C/D layout: col = cg*16 + r, row = kg*4 + reg
        #pragma unroll
        for (int cg = 0; cg < 4; ++cg)
            #pragma unroll
            for (int rr = 0; rr < 4; ++rr) {
                part[(size_t)bid * 2048 + (kg * 4 + rr) * FOUT + cg * 16 + r]
                    = accA[cg][rr];
                part[(size_t)bid * 2048 + (16 + kg * 4 + rr) * FOUT + cg * 16 + r]
                    = accB[cg][rr];
            }
        if (lane < 32)
            pden[bid * 32 + lane] = dred[0][lane] + dred[1][lane]
                                  + dred[2][lane] + dred[3][lane];
    }
}

// -------- kernel 3: combine KQ partials, normalize, ELU --------
__global__ __launch_bounds__(256) void k_fin(
        const float* __restrict__ part, const float* __restrict__ pden,
        float* __restrict__ out) {
    const int t   = threadIdx.x;
    const int r   = t >> 4;
    const int c4  = (t & 15) * 4;
    const int i   = blockIdx.x * 16 + r;    // output row
    const int rgb = i >> 5;
    const int ro  = i & 31;

    float4 v = make_float4(0.f, 0.f, 0.f, 0.f);
    float den = 0.f;
    #pragma unroll
    for (int p = 0; p < KQ; ++p) {
        const int b2 = rgb * KQ + p;
        const float4 pv = *(const float4*)&part[(size_t)b2 * 2048 + ro * FOUT + c4];
        v.x += pv.x; v.y += pv.y; v.z += pv.z; v.w += pv.w;
        den += pden[b2 * 32 + ro];
    }
    den = fmaxf(den, 1e-30f);
    const float inv = __fdividef(1.f, den);
    float4 o;
    const float h0 = v.x * inv; o.x = (h0 > 0.f) ? h0 : (__expf(h0) - 1.f);
    const float h1 = v.y * inv; o.y = (h1 > 0.f) ? h1 : (__expf(h1) - 1.f);
    const float h2 = v.z * inv; o.z = (h2 > 0.f) ? h2 : (__expf(h2) - 1.f);
    const float h3 = v.w * inv; o.w = (h3 > 0.f) ? h3 : (__expf(h3) - 1.f);
    *(float4*)&out[(size_t)i * FOUT + c4] = o;
}

extern "C" void kernel_launch(void* const* d_in, const int* in_sizes, int n_in,
                              void* d_out, int out_size, void* d_ws, size_t ws_size,
                              hipStream_t stream) {
    const float* X   = (const float*)d_in[0];
    const int*   adj = (const int*)d_in[1];
    const float* W   = (const float*)d_in[2];
    const float* a1  = (const float*)d_in[3];
    const float* a2  = (const float*)d_in[4];
    float* out = (float*)d_out;

    char* ws = (char*)d_ws;
    unsigned short* hb = (unsigned short*)ws;             // 1 MB
    float* f1   = (float*)(ws + (1u << 20));              // 32 KB
    float* f2   = f1 + N;                                 // 32 KB
    ull*   mask = (ull*)(ws + (1u << 20) + (1u << 16));   // 8.4 MB
    float* part = (float*)(ws + (1u << 20) + (1u << 16) + ((size_t)NSPAN * 32));
    float* pden = part + (size_t)2048 * 2048;             // 2048*32 floats

    k_hp  <<<PACKB + N / 16, 256, 0, stream>>>(X, W, a1, a2, adj, hb, f1, f2, mask);
    k_attn<<<(N / RB) * KQ,  256, 0, stream>>>(mask, hb, f1, f2, part, pden);
    k_fin <<<N / 16,         256, 0, stream>>>(part, pden, out);
}

// Round 10
// 103.459 us; speedup vs baseline: 1.5367x; 1.5367x over previous
//
#include <hip/hip_runtime.h>
#include <hip/hip_bf16.h>

#define N     8192
#define FIN   256
#define FOUT  64
#define ALPHA 0.2f
#define KQ    8               // j-split across blocks
#define JQ    (N / KQ)        // 1024 j per block
#define JW    (JQ / 4)        // 256 j per wave
#define NS    (JW / 32)       // 8 MFMA K-steps per wave

typedef __attribute__((ext_vector_type(8))) short bf16x8;
typedef __attribute__((ext_vector_type(4))) float f32x4;
typedef __attribute__((ext_vector_type(4))) int   i32x4;

static __device__ __forceinline__ unsigned short f2bf(float x) {
    union { float f; unsigned int u; } v; v.f = x;
    unsigned int r = v.u + 0x7FFFu + ((v.u >> 16) & 1u);   // RNE
    return (unsigned short)(r >> 16);
}
static __device__ __forceinline__ float asf(unsigned int u) {
    union { unsigned int u; float f; } v; v.u = u; return v.f;
}
// masked exp(leaky_relu(f1+f2)); scores bounded (~15) -> no softmax shift needed
static __device__ __forceinline__ float wcalc(float f1v, float f2v, int a) {
    const float e = f1v + f2v;
    const float lr = fmaxf(e, ALPHA * e);       // leaky relu as max
    const float w = __expf(lr);
    return (a > 0) ? w : 0.f;
}

// ---- kernel 1: h = X@W -> hb[j/8][col][8] (MFMA B-frag layout), f1, f2 ----
__global__ __launch_bounds__(256) void k_h(
        const float* __restrict__ X, const float* __restrict__ W,
        const float* __restrict__ a1, const float* __restrict__ a2,
        unsigned short* __restrict__ hb,
        float* __restrict__ f1, float* __restrict__ f2) {
    const int lane = threadIdx.x & 63;              // = output column
    const int wave = threadIdx.x >> 6;
    const int row0 = (blockIdx.x * 4 + wave) * 4;   // 4 node-rows per wave

    const float4* Xr[4];
    #pragma unroll
    for (int r = 0; r < 4; ++r)
        Xr[r] = (const float4*)(X + (size_t)(row0 + r) * FIN);

    float acc[4] = {0.f, 0.f, 0.f, 0.f};
    #pragma unroll 4
    for (int k4 = 0; k4 < FIN / 4; ++k4) {
        const float w0 = W[(k4 * 4 + 0) * FOUT + lane];
        const float w1 = W[(k4 * 4 + 1) * FOUT + lane];
        const float w2 = W[(k4 * 4 + 2) * FOUT + lane];
        const float w3 = W[(k4 * 4 + 3) * FOUT + lane];
        #pragma unroll
        for (int r = 0; r < 4; ++r) {
            const float4 xv = Xr[r][k4];
            acc[r] = fmaf(xv.x, w0, acc[r]);
            acc[r] = fmaf(xv.y, w1, acc[r]);
            acc[r] = fmaf(xv.z, w2, acc[r]);
            acc[r] = fmaf(xv.w, w3, acc[r]);
        }
    }

    // hb[chunk=row0>>3][col=lane][e=(row0&7)+r], rows row0..row0+3 same chunk
    ushort4 hv;
    hv.x = f2bf(acc[0]); hv.y = f2bf(acc[1]);
    hv.z = f2bf(acc[2]); hv.w = f2bf(acc[3]);
    *(ushort4*)&hb[(size_t)(row0 >> 3) * 512 + lane * 8 + (row0 & 7)] = hv;

    const float a1v = a1[lane];
    const float a2v = a2[lane];
    #pragma unroll
    for (int r = 0; r < 4; ++r) {
        float p1 = acc[r] * a1v;
        float p2 = acc[r] * a2v;
        #pragma unroll
        for (int off = 32; off > 0; off >>= 1) {
            p1 += __shfl_down(p1, off);
            p2 += __shfl_down(p2, off);
        }
        if (lane == 0) { f1[row0 + r] = p1; f2[row0 + r] = p2; }
    }
}

// -------- kernel 2: barrier-free MFMA attention partial sums --------
// block b: row-group b>>3 (16 rows), j-octant b&7; wave owns 256 j (8 K-steps).
// adj prefetch: depth-4 ping-pong (8 dwordx4 outstanding steady-state).
__global__ __launch_bounds__(256, 4) void k_attn(
        const int* __restrict__ adj, const unsigned short* __restrict__ hb,
        const float* __restrict__ f1, const float* __restrict__ f2,
        float* __restrict__ part, float* __restrict__ pden) {
    __shared__ f32x4 red[2][256];    // 8 KB epilogue acc staging
    __shared__ float dred[4][16];

    const int t    = threadIdx.x;
    const int lane = t & 63;
    const int wv   = t >> 6;
    const int bid  = blockIdx.x;
    const int rg   = bid >> 3;
    const int q    = bid & 7;
    const int i0   = rg * 16;
    const int r    = lane & 15;     // A-row / B-col-sub / output col
    const int kg   = lane >> 4;     // k-group within K-step

    const float f1v = f1[i0 + r];
    const int jw = q * JQ + wv * JW;
    const int* aptr = adj + (size_t)(i0 + r) * N + jw + kg * 8;
    const float* f2p = f2 + jw + kg * 8;
    const unsigned short* hbp = hb + (size_t)(jw >> 3) * 512 + kg * 512 + r * 8;

    // ---- depth-4 ping-pong prefetch of adj ----
    i32x4 pf[4][2];
    #pragma unroll
    for (int d = 0; d < 4; ++d) {
        pf[d][0] = *(const i32x4*)(aptr + d * 32);
        pf[d][1] = *(const i32x4*)(aptr + d * 32 + 4);
    }

    f32x4 acc[4];
    #pragma unroll
    for (int c = 0; c < 4; ++c) acc[c] = (f32x4){0.f, 0.f, 0.f, 0.f};
    float sacc = 0.f;

    #pragma unroll
    for (int s = 0; s < NS; ++s) {
        const i32x4 a0 = pf[s & 3][0];
        const i32x4 a1 = pf[s & 3][1];
        if (s + 4 < NS) {
            pf[s & 3][0] = *(const i32x4*)(aptr + (s + 4) * 32);
            pf[s & 3][1] = *(const i32x4*)(aptr + (s + 4) * 32 + 4);
        }

        // B-fragments: coalesced 16B loads (hb is MFMA-native layout, L2-hot)
        const unsigned short* hs = hbp + s * 2048;
        const bf16x8 b0 = *(const bf16x8*)(hs);
        const bf16x8 b1 = *(const bf16x8*)(hs + 128);
        const bf16x8 b2 = *(const bf16x8*)(hs + 256);
        const bf16x8 b3 = *(const bf16x8*)(hs + 384);

        const float4 fa = *(const float4*)(f2p + s * 32);
        const float4 fb = *(const float4*)(f2p + s * 32 + 4);

        const float w0 = wcalc(f1v, fa.x, a0.x);
        const float w1 = wcalc(f1v, fa.y, a0.y);
        const float w2 = wcalc(f1v, fa.z, a0.z);
        const float w3 = wcalc(f1v, fa.w, a0.w);
        const float w4 = wcalc(f1v, fb.x, a1.x);
        const float w5 = wcalc(f1v, fb.y, a1.y);
        const float w6 = wcalc(f1v, fb.z, a1.z);
        const float w7 = wcalc(f1v, fb.w, a1.w);

        // pack to bf16 pairs (v_cvt_pk_bf16_f32) and build A-frag
        union { bf16x8 v; __hip_bfloat162 h2[4]; unsigned int u[4]; } af;
        af.h2[0] = __float22bfloat162_rn(make_float2(w0, w1));
        af.h2[1] = __float22bfloat162_rn(make_float2(w2, w3));
        af.h2[2] = __float22bfloat162_rn(make_float2(w4, w5));
        af.h2[3] = __float22bfloat162_rn(make_float2(w6, w7));

        // denominator from the ROUNDED weights (bit-extract from packed pairs)
        float ds = 0.f;
        #pragma unroll
        for (int u = 0; u < 4; ++u)
            ds += asf(af.u[u] << 16) + asf(af.u[u] & 0xFFFF0000u);
        sacc += ds;

        acc[0] = __builtin_amdgcn_mfma_f32_16x16x32_bf16(af.v, b0, acc[0], 0, 0, 0);
        acc[1] = __builtin_amdgcn_mfma_f32_16x16x32_bf16(af.v, b1, acc[1], 0, 0, 0);
        acc[2] = __builtin_amdgcn_mfma_f32_16x16x32_bf16(af.v, b2, acc[2], 0, 0, 0);
        acc[3] = __builtin_amdgcn_mfma_f32_16x16x32_bf16(af.v, b3, acc[3], 0, 0, 0);
    }

    // ---- denominator: lanes l, l+16, l+32, l+48 share a row ----
    sacc += __shfl_xor(sacc, 16);
    sacc += __shfl_xor(sacc, 32);
    if (lane < 16) dred[wv][lane] = sacc;

    // ---- acc tree-reduce across the 4 waves ----
    __syncthreads();
    if (wv >= 2) {
        #pragma unroll
        for (int cg = 0; cg < 4; ++cg) red[wv - 2][lane * 4 + cg] = acc[cg];
    }
    __syncthreads();
    if (wv < 2) {
        #pragma unroll
        for (int cg = 0; cg < 4; ++cg) acc[cg] += red[wv][lane * 4 + cg];
    }
    __syncthreads();
    if (wv == 1) {
        #pragma unroll
        for (int cg = 0; cg < 4; ++cg) red[0][lane * 4 + cg] = acc[cg];
    }
    __syncthreads();
    if (wv == 0) {
        #pragma unroll
        for (int cg = 0; cg < 4; ++cg) acc[cg] += red[0][lane * 4 + cg];
        // C/D layout: col = cg*16 + r, row = kg*4 + reg. NT: part is
        // write-once-read-once -> keep it out of L3 (protect adj residency)
        #pragma unroll
        for (int cg = 0; cg < 4; ++cg)
            #pragma unroll
            for (int rr = 0; rr < 4; ++rr)
                __builtin_nontemporal_store(acc[cg][rr],
                    &part[(size_t)bid * 1024 + (kg * 4 + rr) * FOUT + cg * 16 + r]);
        if (lane < 16)
            __builtin_nontemporal_store(
                dred[0][lane] + dred[1][lane] + dred[2][lane] + dred[3][lane],
                &pden[bid * 16 + lane]);
    }
}

// -------- kernel 3: combine KQ partials, normalize, ELU --------
__global__ __launch_bounds__(256) void k_fin(
        const float* __restrict__ part, const float* __restrict__ pden,
        float* __restrict__ out) {
    const int rg = blockIdx.x;
    const int t  = threadIdx.x;
    const int r  = t >> 4;
    const int c4 = (t & 15) * 4;

    float vx = 0.f, vy = 0.f, vz = 0.f, vw = 0.f;
    float den = 0.f;
    #pragma unroll
    for (int p = 0; p < KQ; ++p) {
        const int blk = rg * KQ + p;
        const f32x4 pv = __builtin_nontemporal_load(
            (const f32x4*)&part[(size_t)blk * 1024 + r * FOUT + c4]);
        vx += pv.x; vy += pv.y; vz += pv.z; vw += pv.w;
        den += __builtin_nontemporal_load(&pden[blk * 16 + r]);
    }
    den = fmaxf(den, 1e-30f);
    const float inv = __fdividef(1.f, den);
    float4 o;
    const float h0 = vx * inv; o.x = (h0 > 0.f) ? h0 : (__expf(h0) - 1.f);
    const float h1 = vy * inv; o.y = (h1 > 0.f) ? h1 : (__expf(h1) - 1.f);
    const float h2 = vz * inv; o.z = (h2 > 0.f) ? h2 : (__expf(h2) - 1.f);
    const float h3 = vw * inv; o.w = (h3 > 0.f) ? h3 : (__expf(h3) - 1.f);
    *(float4*)&out[(size_t)(rg * 16 + r) * FOUT + c4] = o;
}

extern "C" void kernel_launch(void* const* d_in, const int* in_sizes, int n_in,
                              void* d_out, int out_size, void* d_ws, size_t ws_size,
                              hipStream_t stream) {
    const float* X   = (const float*)d_in[0];
    const int*   adj = (const int*)d_in[1];
    const float* W   = (const float*)d_in[2];
    const float* a1  = (const float*)d_in[3];
    const float* a2  = (const float*)d_in[4];
    float* out = (float*)d_out;

    unsigned short* hb = (unsigned short*)d_ws;                   // 1 MB
    float* f1   = (float*)((char*)d_ws + (size_t)FOUT * N * 2);   // N floats
    float* f2   = f1 + N;                                         // N floats
    float* part = f2 + N;                                         // 4096*1024 floats
    float* pden = part + (size_t)(N / 16) * KQ * 1024;            // 4096*16 floats

    k_h   <<<N / 16, 256, 0, stream>>>(X, W, a1, a2, hb, f1, f2);
    k_attn<<<(N / 16) * KQ, 256, 0, stream>>>(adj, hb, f1, f2, part, pden);
    k_fin <<<N / 16, 256, 0, stream>>>(part, pden, out);
}

// Round 11
// 98.657 us; speedup vs baseline: 1.6115x; 1.0487x over previous
//
#include <hip/hip_runtime.h>
#include <hip/hip_bf16.h>

#define N     8192
#define FIN   256
#define FOUT  64
#define ALPHA 0.2f
#define KQ    16              // j-split across blocks
#define JQ    (N / KQ)        // 512 j per block
#define JW    (JQ / 4)        // 128 j per wave
#define NS    (JW / 32)       // 4 MFMA K-steps per wave

typedef __attribute__((ext_vector_type(8))) short bf16x8;
typedef __attribute__((ext_vector_type(4))) float f32x4;
typedef __attribute__((ext_vector_type(4))) int   i32x4;

static __device__ __forceinline__ unsigned short f2bf(float x) {
    union { float f; unsigned int u; } v; v.f = x;
    unsigned int r = v.u + 0x7FFFu + ((v.u >> 16) & 1u);   // RNE
    return (unsigned short)(r >> 16);
}
static __device__ __forceinline__ float asf(unsigned int u) {
    union { unsigned int u; float f; } v; v.u = u; return v.f;
}
// masked exp(leaky_relu(f1+f2)); scores bounded (~15) -> no softmax shift needed
static __device__ __forceinline__ float wcalc(float f1v, float f2v, int a) {
    const float e = f1v + f2v;
    const float lr = fmaxf(e, ALPHA * e);       // leaky relu as max
    const float w = __expf(lr);
    return (a > 0) ? w : 0.f;
}

// ---- kernel 1: h = X@W -> hb[j/8][col][8] (MFMA B-frag layout), f1, f2 ----
__global__ __launch_bounds__(256) void k_h(
        const float* __restrict__ X, const float* __restrict__ W,
        const float* __restrict__ a1, const float* __restrict__ a2,
        unsigned short* __restrict__ hb,
        float* __restrict__ f1, float* __restrict__ f2) {
    const int lane = threadIdx.x & 63;              // = output column
    const int wave = threadIdx.x >> 6;
    const int row0 = (blockIdx.x * 4 + wave) * 4;   // 4 node-rows per wave

    typedef __attribute__((ext_vector_type(4))) float f4;
    const f4* Xr[4];
    #pragma unroll
    for (int r = 0; r < 4; ++r)
        Xr[r] = (const f4*)(X + (size_t)(row0 + r) * FIN);

    float acc[4] = {0.f, 0.f, 0.f, 0.f};
    #pragma unroll 4
    for (int k4 = 0; k4 < FIN / 4; ++k4) {
        const float w0 = W[(k4 * 4 + 0) * FOUT + lane];
        const float w1 = W[(k4 * 4 + 1) * FOUT + lane];
        const float w2 = W[(k4 * 4 + 2) * FOUT + lane];
        const float w3 = W[(k4 * 4 + 3) * FOUT + lane];
        #pragma unroll
        for (int r = 0; r < 4; ++r) {
            // NT: X is read exactly once per launch -> don't evict adj from L3
            const f4 xv = __builtin_nontemporal_load(&Xr[r][k4]);
            acc[r] = fmaf(xv.x, w0, acc[r]);
            acc[r] = fmaf(xv.y, w1, acc[r]);
            acc[r] = fmaf(xv.z, w2, acc[r]);
            acc[r] = fmaf(xv.w, w3, acc[r]);
        }
    }

    // hb[chunk=row0>>3][col=lane][e=(row0&7)+r], rows row0..row0+3 same chunk
    ushort4 hv;
    hv.x = f2bf(acc[0]); hv.y = f2bf(acc[1]);
    hv.z = f2bf(acc[2]); hv.w = f2bf(acc[3]);
    *(ushort4*)&hb[(size_t)(row0 >> 3) * 512 + lane * 8 + (row0 & 7)] = hv;

    const float a1v = a1[lane];
    const float a2v = a2[lane];
    #pragma unroll
    for (int r = 0; r < 4; ++r) {
        float p1 = acc[r] * a1v;
        float p2 = acc[r] * a2v;
        #pragma unroll
        for (int off = 32; off > 0; off >>= 1) {
            p1 += __shfl_down(p1, off);
            p2 += __shfl_down(p2, off);
        }
        if (lane == 0) { f1[row0 + r] = p1; f2[row0 + r] = p2; }
    }
}

// -------- kernel 2: barrier-free MFMA attention partial sums --------
// block b: row-group b>>4 (16 rows), j-sixteenth b&15; wave owns 128 j.
// Wave's ENTIRE adj window (8 x dwordx4) issues in the prologue; higher
// occupancy (6 waves/SIMD) provides the in-flight depth.
__global__ __launch_bounds__(256, 6) void k_attn(
        const int* __restrict__ adj, const unsigned short* __restrict__ hb,
        const float* __restrict__ f1, const float* __restrict__ f2,
        float* __restrict__ part, float* __restrict__ pden) {
    __shared__ f32x4 red[2][256];    // 8 KB epilogue acc staging
    __shared__ float dred[4][16];

    const int t    = threadIdx.x;
    const int lane = t & 63;
    const int wv   = t >> 6;
    const int bid  = blockIdx.x;
    const int rg   = bid >> 4;
    const int q    = bid & 15;
    const int i0   = rg * 16;
    const int r    = lane & 15;     // A-row / B-col-sub / output col
    const int kg   = lane >> 4;     // k-group within K-step

    const float f1v = f1[i0 + r];
    const int jw = q * JQ + wv * JW;
    const int* aptr = adj + (size_t)(i0 + r) * N + jw + kg * 8;
    const float* f2p = f2 + jw + kg * 8;
    const unsigned short* hbp = hb + (size_t)(jw >> 3) * 512 + kg * 512 + r * 8;

    // ---- prologue: the wave's entire adj window, 8 independent loads ----
    i32x4 am[2 * NS];
    #pragma unroll
    for (int s = 0; s < NS; ++s) {
        am[2 * s]     = *(const i32x4*)(aptr + s * 32);
        am[2 * s + 1] = *(const i32x4*)(aptr + s * 32 + 4);
    }

    f32x4 acc[4];
    #pragma unroll
    for (int c = 0; c < 4; ++c) acc[c] = (f32x4){0.f, 0.f, 0.f, 0.f};
    float sacc = 0.f;

    #pragma unroll
    for (int s = 0; s < NS; ++s) {
        // B-fragments: coalesced 16B loads (hb is MFMA-native layout, L2-hot)
        const unsigned short* hs = hbp + s * 2048;
        const bf16x8 b0 = *(const bf16x8*)(hs);
        const bf16x8 b1 = *(const bf16x8*)(hs + 128);
        const bf16x8 b2 = *(const bf16x8*)(hs + 256);
        const bf16x8 b3 = *(const bf16x8*)(hs + 384);

        const float4 fa = *(const float4*)(f2p + s * 32);
        const float4 fb = *(const float4*)(f2p + s * 32 + 4);
        const i32x4 a0 = am[2 * s];
        const i32x4 a1 = am[2 * s + 1];

        const float w0 = wcalc(f1v, fa.x, a0.x);
        const float w1 = wcalc(f1v, fa.y, a0.y);
        const float w2 = wcalc(f1v, fa.z, a0.z);
        const float w3 = wcalc(f1v, fa.w, a0.w);
        const float w4 = wcalc(f1v, fb.x, a1.x);
        const float w5 = wcalc(f1v, fb.y, a1.y);
        const float w6 = wcalc(f1v, fb.z, a1.z);
        const float w7 = wcalc(f1v, fb.w, a1.w);

        // pack to bf16 pairs (v_cvt_pk_bf16_f32) and build A-frag
        union { bf16x8 v; __hip_bfloat162 h2[4]; unsigned int u[4]; } af;
        af.h2[0] = __float22bfloat162_rn(make_float2(w0, w1));
        af.h2[1] = __float22bfloat162_rn(make_float2(w2, w3));
        af.h2[2] = __float22bfloat162_rn(make_float2(w4, w5));
        af.h2[3] = __float22bfloat162_rn(make_float2(w6, w7));

        // denominator from the ROUNDED weights (bit-extract from packed pairs)
        float ds = 0.f;
        #pragma unroll
        for (int u = 0; u < 4; ++u)
            ds += asf(af.u[u] << 16) + asf(af.u[u] & 0xFFFF0000u);
        sacc += ds;

        acc[0] = __builtin_amdgcn_mfma_f32_16x16x32_bf16(af.v, b0, acc[0], 0, 0, 0);
        acc[1] = __builtin_amdgcn_mfma_f32_16x16x32_bf16(af.v, b1, acc[1], 0, 0, 0);
        acc[2] = __builtin_amdgcn_mfma_f32_16x16x32_bf16(af.v, b2, acc[2], 0, 0, 0);
        acc[3] = __builtin_amdgcn_mfma_f32_16x16x32_bf16(af.v, b3, acc[3], 0, 0, 0);
    }

    // ---- denominator: lanes l, l+16, l+32, l+48 share a row ----
    sacc += __shfl_xor(sacc, 16);
    sacc += __shfl_xor(sacc, 32);
    if (lane < 16) dred[wv][lane] = sacc;

    // ---- acc tree-reduce across the 4 waves ----
    __syncthreads();
    if (wv >= 2) {
        #pragma unroll
        for (int cg = 0; cg < 4; ++cg) red[wv - 2][lane * 4 + cg] = acc[cg];
    }
    __syncthreads();
    if (wv < 2) {
        #pragma unroll
        for (int cg = 0; cg < 4; ++cg) acc[cg] += red[wv][lane * 4 + cg];
    }
    __syncthreads();
    if (wv == 1) {
        #pragma unroll
        for (int cg = 0; cg < 4; ++cg) red[0][lane * 4 + cg] = acc[cg];
    }
    __syncthreads();
    if (wv == 0) {
        #pragma unroll
        for (int cg = 0; cg < 4; ++cg) acc[cg] += red[0][lane * 4 + cg];
        // C/D layout: col = cg*16 + r, row = kg*4 + reg. NT: part is
        // write-once-read-once -> keep it out of L3 (protect adj residency)
        #pragma unroll
        for (int cg = 0; cg < 4; ++cg)
            #pragma unroll
            for (int rr = 0; rr < 4; ++rr)
                __builtin_nontemporal_store(acc[cg][rr],
                    &part[(size_t)bid * 1024 + (kg * 4 + rr) * FOUT + cg * 16 + r]);
        if (lane < 16)
            __builtin_nontemporal_store(
                dred[0][lane] + dred[1][lane] + dred[2][lane] + dred[3][lane],
                &pden[bid * 16 + lane]);
    }
}

// -------- kernel 3: combine KQ partials, normalize, ELU --------
__global__ __launch_bounds__(256) void k_fin(
        const float* __restrict__ part, const float* __restrict__ pden,
        float* __restrict__ out) {
    const int rg = blockIdx.x;
    const int t  = threadIdx.x;
    const int r  = t >> 4;
    const int c4 = (t & 15) * 4;

    float vx = 0.f, vy = 0.f, vz = 0.f, vw = 0.f;
    float den = 0.f;
    #pragma unroll
    for (int p = 0; p < KQ; ++p) {
        const int blk = rg * KQ + p;
        const f32x4 pv = __builtin_nontemporal_load(
            (const f32x4*)&part[(size_t)blk * 1024 + r * FOUT + c4]);
        vx += pv.x; vy += pv.y; vz += pv.z; vw += pv.w;
        den += __builtin_nontemporal_load(&pden[blk * 16 + r]);
    }
    den = fmaxf(den, 1e-30f);
    const float inv = __fdividef(1.f, den);
    f32x4 o;
    const float h0 = vx * inv; o.x = (h0 > 0.f) ? h0 : (__expf(h0) - 1.f);
    const float h1 = vy * inv; o.y = (h1 > 0.f) ? h1 : (__expf(h1) - 1.f);
    const float h2 = vz * inv; o.z = (h2 > 0.f) ? h2 : (__expf(h2) - 1.f);
    const float h3 = vw * inv; o.w = (h3 > 0.f) ? h3 : (__expf(h3) - 1.f);
    __builtin_nontemporal_store(o,
        (f32x4*)&out[(size_t)(rg * 16 + r) * FOUT + c4]);
}

extern "C" void kernel_launch(void* const* d_in, const int* in_sizes, int n_in,
                              void* d_out, int out_size, void* d_ws, size_t ws_size,
                              hipStream_t stream) {
    const float* X   = (const float*)d_in[0];
    const int*   adj = (const int*)d_in[1];
    const float* W   = (const float*)d_in[2];
    const float* a1  = (const float*)d_in[3];
    const float* a2  = (const float*)d_in[4];
    float* out = (float*)d_out;

    unsigned short* hb = (unsigned short*)d_ws;                   // 1 MB
    float* f1   = (float*)((char*)d_ws + (size_t)FOUT * N * 2);   // N floats
    float* f2   = f1 + N;                                         // N floats
    float* part = f2 + N;                                         // 8192*1024 floats
    float* pden = part + (size_t)(N / 16) * KQ * 1024;            // 8192*16 floats

    k_h   <<<N / 16, 256, 0, stream>>>(X, W, a1, a2, hb, f1, f2);
    k_attn<<<(N / 16) * KQ, 256, 0, stream>>>(adj, hb, f1, f2, part, pden);
    k_fin <<<N / 16, 256, 0, stream>>>(part, pden, out);
}

// Round 12
// 86.750 us; speedup vs baseline: 1.8327x; 1.1373x over previous
//
#include <hip/hip_runtime.h>
#include <hip/hip_bf16.h>

#define N     8192
#define FIN   256
#define FOUT  64
#define ALPHA 0.2f
#define KQ    8               // j-split across blocks
#define JQ    (N / KQ)        // 1024 j per block
#define TJ    256             // j per LDS tile
#define NTL   (JQ / TJ)       // 4 tiles per block
#define NSW   2               // K-steps per wave per tile (8 steps / 4 waves)

typedef __attribute__((ext_vector_type(8))) short bf16x8;
typedef __attribute__((ext_vector_type(4))) float f32x4;
typedef __attribute__((ext_vector_type(4))) int   i32x4;

static __device__ __forceinline__ unsigned short f2bf(float x) {
    union { float f; unsigned int u; } v; v.f = x;
    unsigned int r = v.u + 0x7FFFu + ((v.u >> 16) & 1u);   // RNE
    return (unsigned short)(r >> 16);
}
static __device__ __forceinline__ float asf(unsigned int u) {
    union { unsigned int u; float f; } v; v.u = u; return v.f;
}
// masked exp(leaky_relu(f1+f2)); scores bounded (~15) -> no softmax shift needed
static __device__ __forceinline__ float wcalc(float f1v, float f2v, int a) {
    const float e = f1v + f2v;
    const float lr = fmaxf(e, ALPHA * e);
    const float w = __expf(lr);
    return (a > 0) ? w : 0.f;
}
// posted 16B/lane global->LDS copy (no VGPR return)
static __device__ __forceinline__ void gload_lds16(const int* g, int* l) {
    __builtin_amdgcn_global_load_lds(
        (const __attribute__((address_space(1))) void*)g,
        (__attribute__((address_space(3))) void*)l,
        16, 0, 0);
}
// per-row chunk permutation (bank spread for the row-scattered consume)
static __device__ __forceinline__ int rowperm(int row) {
    return ((row << 1) | (row >> 3)) & 63;
}

// ---- kernel 1: h = X@W -> hb[j/8][col][8] (MFMA B-frag layout), f1, f2 ----
__global__ __launch_bounds__(256) void k_h(
        const float* __restrict__ X, const float* __restrict__ W,
        const float* __restrict__ a1, const float* __restrict__ a2,
        unsigned short* __restrict__ hb,
        float* __restrict__ f1, float* __restrict__ f2) {
    const int lane = threadIdx.x & 63;
    const int wave = threadIdx.x >> 6;
    const int row0 = (blockIdx.x * 4 + wave) * 4;

    const f32x4* Xr[4];
    #pragma unroll
    for (int r = 0; r < 4; ++r)
        Xr[r] = (const f32x4*)(X + (size_t)(row0 + r) * FIN);

    float acc[4] = {0.f, 0.f, 0.f, 0.f};
    #pragma unroll 4
    for (int k4 = 0; k4 < FIN / 4; ++k4) {
        const float w0 = W[(k4 * 4 + 0) * FOUT + lane];
        const float w1 = W[(k4 * 4 + 1) * FOUT + lane];
        const float w2 = W[(k4 * 4 + 2) * FOUT + lane];
        const float w3 = W[(k4 * 4 + 3) * FOUT + lane];
        #pragma unroll
        for (int r = 0; r < 4; ++r) {
            const f32x4 xv = __builtin_nontemporal_load(&Xr[r][k4]);
            acc[r] = fmaf(xv.x, w0, acc[r]);
            acc[r] = fmaf(xv.y, w1, acc[r]);
            acc[r] = fmaf(xv.z, w2, acc[r]);
            acc[r] = fmaf(xv.w, w3, acc[r]);
        }
    }

    ushort4 hv;
    hv.x = f2bf(acc[0]); hv.y = f2bf(acc[1]);
    hv.z = f2bf(acc[2]); hv.w = f2bf(acc[3]);
    *(ushort4*)&hb[(size_t)(row0 >> 3) * 512 + lane * 8 + (row0 & 7)] = hv;

    const float a1v = a1[lane];
    const float a2v = a2[lane];
    #pragma unroll
    for (int r = 0; r < 4; ++r) {
        float p1 = acc[r] * a1v;
        float p2 = acc[r] * a2v;
        #pragma unroll
        for (int off = 32; off > 0; off >>= 1) {
            p1 += __shfl_down(p1, off);
            p2 += __shfl_down(p2, off);
        }
        if (lane == 0) { f1[row0 + r] = p1; f2[row0 + r] = p2; }
    }
}

// -------- kernel 2: LDS-staged-adj MFMA attention partial sums --------
// block b: rows (b>>3)*16..+15, j-window (b&7)*1024. 4 tiles of 256 j;
// adj staged via posted global_load_lds (1 KB contiguous per instruction),
// pipelined one tile ahead with counted vmcnt + raw barriers.
__global__ __launch_bounds__(256) void k_attn(
        const int* __restrict__ adj, const unsigned short* __restrict__ hb,
        const float* __restrict__ f1, const float* __restrict__ f2,
        float* __restrict__ part, float* __restrict__ pden) {
    __shared__ int  tile[2][16][TJ];   // 32 KB adj double buffer
    __shared__ f32x4 red[2][256];      // 8 KB epilogue acc staging
    __shared__ float dred[4][16];

    const int t    = threadIdx.x;
    const int lane = t & 63;
    const int wv   = t >> 6;
    const int bid  = blockIdx.x;
    const int rg   = bid >> 3;
    const int q    = bid & 7;
    const int i0   = rg * 16;
    const int r    = lane & 15;     // A-row / output col
    const int kg   = lane >> 4;     // k-group within K-step

    const float f1v = f1[i0 + r];
    const int jb = q * JQ;
    const int pr = rowperm(r);

    f32x4 acc[4];
    #pragma unroll
    for (int c = 0; c < 4; ++c) acc[c] = (f32x4){0.f, 0.f, 0.f, 0.f};
    float sacc = 0.f;

    // ---- prologue: stage tile 0 ----
    #pragma unroll
    for (int rr = 0; rr < 4; ++rr) {
        const int row = wv * 4 + rr;
        gload_lds16(adj + (size_t)(i0 + row) * N + jb + (lane ^ rowperm(row)) * 4,
                    &tile[0][row][0]);
    }
    asm volatile("s_waitcnt vmcnt(0)" ::: "memory");
    __builtin_amdgcn_s_barrier();

    int buf = 0;
    for (int tt = 0; tt < NTL; ++tt) {
        const int jt = jb + tt * TJ;

        // ---- issue this tile's hb/f2 register loads FIRST (vmcnt FIFO) ----
        bf16x8 bfr[NSW][4];
        float4 fa[NSW], fb[NSW];
        #pragma unroll
        for (int ss = 0; ss < NSW; ++ss) {
            const int s = wv * NSW + ss;
            const float* f2s = f2 + jt + s * 32 + kg * 8;
            fa[ss] = *(const float4*)(f2s);
            fb[ss] = *(const float4*)(f2s + 4);
            const unsigned short* hs =
                hb + (size_t)((jt >> 3) + s * 4 + kg) * 512 + r * 8;
            bfr[ss][0] = *(const bf16x8*)(hs);
            bfr[ss][1] = *(const bf16x8*)(hs + 128);
            bfr[ss][2] = *(const bf16x8*)(hs + 256);
            bfr[ss][3] = *(const bf16x8*)(hs + 384);
        }
        __builtin_amdgcn_sched_barrier(0);

        // ---- post next tile's stages (stay in flight across consume) ----
        if (tt + 1 < NTL) {
            #pragma unroll
            for (int rr = 0; rr < 4; ++rr) {
                const int row = wv * 4 + rr;
                gload_lds16(adj + (size_t)(i0 + row) * N + jt + TJ
                                + (lane ^ rowperm(row)) * 4,
                            &tile[buf ^ 1][row][0]);
            }
            __builtin_amdgcn_sched_barrier(0);
            asm volatile("s_waitcnt vmcnt(4)" ::: "memory");  // keep 4 posted
        } else {
            asm volatile("s_waitcnt vmcnt(0)" ::: "memory");
        }
        __builtin_amdgcn_s_barrier();     // tile[buf] fully staged, regs ready

        // ---- consume: masks from LDS, weights -> bf16 A-frag -> MFMA ----
        #pragma unroll
        for (int ss = 0; ss < NSW; ++ss) {
            const int s = wv * NSW + ss;
            const int g0 = s * 8 + kg * 2;
            const i32x4 a0 = *(const i32x4*)&tile[buf][r][((g0 ^ pr) & 63) * 4];
            const i32x4 a1 = *(const i32x4*)&tile[buf][r][(((g0 + 1) ^ pr) & 63) * 4];

            const float w0 = wcalc(f1v, fa[ss].x, a0.x);
            const float w1 = wcalc(f1v, fa[ss].y, a0.y);
            const float w2 = wcalc(f1v, fa[ss].z, a0.z);
            const float w3 = wcalc(f1v, fa[ss].w, a0.w);
            const float w4 = wcalc(f1v, fb[ss].x, a1.x);
            const float w5 = wcalc(f1v, fb[ss].y, a1.y);
            const float w6 = wcalc(f1v, fb[ss].z, a1.z);
            const float w7 = wcalc(f1v, fb[ss].w, a1.w);

            union { bf16x8 v; __hip_bfloat162 h2[4]; unsigned int u[4]; } af;
            af.h2[0] = __float22bfloat162_rn(make_float2(w0, w1));
            af.h2[1] = __float22bfloat162_rn(make_float2(w2, w3));
            af.h2[2] = __float22bfloat162_rn(make_float2(w4, w5));
            af.h2[3] = __float22bfloat162_rn(make_float2(w6, w7));

            float ds = 0.f;
            #pragma unroll
            for (int u = 0; u < 4; ++u)
                ds += asf(af.u[u] << 16) + asf(af.u[u] & 0xFFFF0000u);
            sacc += ds;

            acc[0] = __builtin_amdgcn_mfma_f32_16x16x32_bf16(af.v, bfr[ss][0], acc[0], 0, 0, 0);
            acc[1] = __builtin_amdgcn_mfma_f32_16x16x32_bf16(af.v, bfr[ss][1], acc[1], 0, 0, 0);
            acc[2] = __builtin_amdgcn_mfma_f32_16x16x32_bf16(af.v, bfr[ss][2], acc[2], 0, 0, 0);
            acc[3] = __builtin_amdgcn_mfma_f32_16x16x32_bf16(af.v, bfr[ss][3], acc[3], 0, 0, 0);
        }
        __builtin_amdgcn_s_barrier();     // all waves done reading tile[buf]
        buf ^= 1;
    }

    // ---- denominator: lanes l, l+16, l+32, l+48 share a row ----
    sacc += __shfl_xor(sacc, 16);
    sacc += __shfl_xor(sacc, 32);
    if (lane < 16) dred[wv][lane] = sacc;

    // ---- acc tree-reduce across the 4 waves ----
    __syncthreads();
    if (wv >= 2) {
        #pragma unroll
        for (int cg = 0; cg < 4; ++cg) red[wv - 2][lane * 4 + cg] = acc[cg];
    }
    __syncthreads();
    if (wv < 2) {
        #pragma unroll
        for (int cg = 0; cg < 4; ++cg) acc[cg] += red[wv][lane * 4 + cg];
    }
    __syncthreads();
    if (wv == 1) {
        #pragma unroll
        for (int cg = 0; cg < 4; ++cg) red[0][lane * 4 + cg] = acc[cg];
    }
    __syncthreads();
    if (wv == 0) {
        #pragma unroll
        for (int cg = 0; cg < 4; ++cg) acc[cg] += red[0][lane * 4 + cg];
        #pragma unroll
        for (int cg = 0; cg < 4; ++cg)
            #pragma unroll
            for (int rr = 0; rr < 4; ++rr)
                __builtin_nontemporal_store(acc[cg][rr],
                    &part[(size_t)bid * 1024 + (kg * 4 + rr) * FOUT + cg * 16 + r]);
        if (lane < 16)
            __builtin_nontemporal_store(
                dred[0][lane] + dred[1][lane] + dred[2][lane] + dred[3][lane],
                &pden[bid * 16 + lane]);
    }
}

// -------- kernel 3: combine KQ partials, normalize, ELU --------
__global__ __launch_bounds__(256) void k_fin(
        const float* __restrict__ part, const float* __restrict__ pden,
        float* __restrict__ out) {
    const int rg = blockIdx.x;
    const int t  = threadIdx.x;
    const int r  = t >> 4;
    const int c4 = (t & 15) * 4;

    float vx = 0.f, vy = 0.f, vz = 0.f, vw = 0.f;
    float den = 0.f;
    #pragma unroll
    for (int p = 0; p < KQ; ++p) {
        const int blk = rg * KQ + p;
        const f32x4 pv = __builtin_nontemporal_load(
            (const f32x4*)&part[(size_t)blk * 1024 + r * FOUT + c4]);
        vx += pv.x; vy += pv.y; vz += pv.z; vw += pv.w;
        den += __builtin_nontemporal_load(&pden[blk * 16 + r]);
    }
    den = fmaxf(den, 1e-30f);
    const float inv = __fdividef(1.f, den);
    f32x4 o;
    const float h0 = vx * inv; o.x = (h0 > 0.f) ? h0 : (__expf(h0) - 1.f);
    const float h1 = vy * inv; o.y = (h1 > 0.f) ? h1 : (__expf(h1) - 1.f);
    const float h2 = vz * inv; o.z = (h2 > 0.f) ? h2 : (__expf(h2) - 1.f);
    const float h3 = vw * inv; o.w = (h3 > 0.f) ? h3 : (__expf(h3) - 1.f);
    __builtin_nontemporal_store(o,
        (f32x4*)&out[(size_t)(rg * 16 + r) * FOUT + c4]);
}

extern "C" void kernel_launch(void* const* d_in, const int* in_sizes, int n_in,
                              void* d_out, int out_size, void* d_ws, size_t ws_size,
                              hipStream_t stream) {
    const float* X   = (const float*)d_in[0];
    const int*   adj = (const int*)d_in[1];
    const float* W   = (const float*)d_in[2];
    const float* a1  = (const float*)d_in[3];
    const float* a2  = (const float*)d_in[4];
    float* out = (float*)d_out;

    unsigned short* hb = (unsigned short*)d_ws;                   // 1 MB
    float* f1   = (float*)((char*)d_ws + (size_t)FOUT * N * 2);   // N floats
    float* f2   = f1 + N;                                         // N floats
    float* part = f2 + N;                                         // 4096*1024 floats
    float* pden = part + (size_t)(N / 16) * KQ * 1024;            // 4096*16 floats

    k_h   <<<N / 16, 256, 0, stream>>>(X, W, a1, a2, hb, f1, f2);
    k_attn<<<(N / 16) * KQ, 256, 0, stream>>>(adj, hb, f1, f2, part, pden);
    k_fin <<<N / 16, 256, 0, stream>>>(part, pden, out);
}